// Round 13
// baseline (277.645 us; speedup 1.0000x reference)
//
#include <hip/hip_runtime.h>

#define Nn 8192
#define Bb 4
#define KK 20
#define OO 64
#define EPSF 1e-5f
#define SLOPEF 0.2f

#define NBUCK 56
#define CAP 120               // per-row candidate list; refine loop handles overflow
#define BOFF 476              // (bits(2^-8) >> 21)
#define CLO 0.00390625f       // 2^-8
#define CHI 63.9999961853f    // largest float < 64 -> coarse bucket <= 55
#define XBINS 256
#define XSCALE 25.6f          // bins over x in [-5, 5]
#define XOFF 5.0f

// ---------------- counting sort by x-bin: sx (sorted float4), ord (sorted->orig), cum -------

__global__ __launch_bounds__(1024) void sort_kernel(const float* __restrict__ x,
                                                    float4* __restrict__ sx,
                                                    int* __restrict__ ord,
                                                    int* __restrict__ cumg) {
  __shared__ unsigned hcnt[XBINS];
  __shared__ unsigned base[XBINS];
  __shared__ unsigned char binb[Nn];
  const int b = blockIdx.x;
  const float* xb = x + b * 3 * Nn;
  for (int t = threadIdx.x; t < XBINS; t += 1024) hcnt[t] = 0u;
  __syncthreads();
  for (int j = threadIdx.x; j < Nn; j += 1024) {
    float a0 = xb[j];
    int bin = (int)((a0 + XOFF) * XSCALE);               // monotone in x
    bin = bin < 0 ? 0 : (bin > XBINS - 1 ? XBINS - 1 : bin);
    binb[j] = (unsigned char)bin;
    atomicAdd(&hcnt[bin], 1u);
  }
  __syncthreads();
  if (threadIdx.x == 0) {
    unsigned run = 0;
    #pragma unroll 8
    for (int i = 0; i < XBINS; ++i) {
      base[i] = run;
      cumg[b * (XBINS + 1) + i] = (int)run;
      run += hcnt[i];
    }
    cumg[b * (XBINS + 1) + XBINS] = (int)run;            // = 8192
  }
  __syncthreads();
  for (int j = threadIdx.x; j < Nn; j += 1024) {
    float a0 = xb[j], a1 = xb[Nn + j], a2 = xb[2 * Nn + j];
    unsigned slot = atomicAdd(&base[binb[j]], 1u);       // in-bin order arbitrary (keys carry
    sx[b * Nn + slot] = make_float4(a0, a1, a2, a0 * a0 + a1 * a1 + a2 * a2);
    ord[b * Nn + slot] = j;                              //  orig idx -> order-independent)
  }
}

// ---------------- KNN: exact top-20, 4 ROWS PER WAVE, x-window + histogram refinement -------
// Wave owns 4 CONSECUTIVE sorted rows (windows ~99% overlapping): each loaded point serves
// 4 rows' distance tests -> 4x fewer loads per row-eval and ~2x less loop scaffolding.
// Groups strided over blocks (g = wid*512 + blockIdx.x) for balance. No __syncthreads;
// per-wave/per-row LDS slices; order-free atomic append (P3 rank-selects by key).
// Exactness per row, as R10-R12 (proven): shared 512-pt subset hist -> valid upper bound
// Tup[q] (any subset gives a valid bound); testing d<Tup[q] over the UNION window equals
// scanning row q's own window (outside it, d >= dx^2 >= Tup[q]); refine loop on overflow
// (monotone quantized accept, bit-identical recompute); ultimate 20-round wave-min path.
// All paths exact; deterministic (keys = (dist-bits, orig idx), distinct).

__global__ __launch_bounds__(256, 8) void knn_kernel(const float4* __restrict__ sx,
                                                     const int* __restrict__ ord,
                                                     const int* __restrict__ cumg,
                                                     int* __restrict__ idx_out) {
  __shared__ unsigned hist[4][4][64];                //  4096 B  [wave][row][bucket]
  __shared__ unsigned long long cdk[4][4][CAP];      // 15360 B  [wave][row][slot]
  __shared__ unsigned ccnt[4][4];

  const int lane = threadIdx.x & 63;
  const int wid  = threadIdx.x >> 6;
  const int b    = blockIdx.y;
  const int g    = (wid << 9) + blockIdx.x;          // strided group id (wave-uniform)
  const int r0   = g << 2;                           // rows r0 .. r0+3

  const float4* __restrict__ sxb  = sx + b * Nn;
  const int*    __restrict__ ordb = ord + b * Nn;
  const int*    __restrict__ cumb = cumg + b * (XBINS + 1);

  float4 me[4];
  #pragma unroll
  for (int q = 0; q < 4; ++q) me[q] = sxb[r0 + q];

  #pragma unroll
  for (int q = 0; q < 4; ++q) hist[wid][q][lane] = 0u;
  if (lane < 4) ccnt[wid][lane] = 0u;

  // ---- P1: coarse hists of the 512 sorted points centered on the group ----
  int sub0 = r0 + 2 - 256; sub0 = sub0 < 0 ? 0 : (sub0 > Nn - 512 ? Nn - 512 : sub0);
  #pragma unroll 2
  for (int i = 0; i < 8; ++i) {
    float4 p = sxb[sub0 + i * 64 + lane];
    #pragma unroll
    for (int q = 0; q < 4; ++q) {
      float inner = fmaf(p.x, me[q].x, fmaf(p.y, me[q].y, p.z * me[q].z));
      float d  = fmaf(-2.0f, inner, me[q].w + p.w);
      float dc = __builtin_amdgcn_fmed3f(d, CLO, CHI);
      atomicAdd(&hist[wid][q][(__float_as_uint(dc) >> 21) - BOFF], 1u);
    }
  }

  // ---- per-row scan -> Tup[q]; windows; union ----
  float Tup[4]; int rlo[4], rhi[4];
  int rloU = Nn, rhiU = 0;
  #pragma unroll
  for (int q = 0; q < 4; ++q) {
    unsigned cum = (lane < NBUCK) ? hist[wid][q][lane] : 0u;
    #pragma unroll
    for (int off = 1; off < 64; off <<= 1) {
      unsigned o = __shfl_up(cum, off);
      if (lane >= off) cum += o;
    }
    int crit = __popcll(__ballot(lane < NBUCK && cum < KK));
    Tup[q] = (crit >= NBUCK - 1) ? 256.0f
                                 : __uint_as_float((unsigned)(BOFF + crit + 1) << 21);
    float rT = sqrtf(Tup[q]);
    int bn_ = (int)((me[q].x - rT - 1e-5f + XOFF) * XSCALE);
    bn_ = bn_ < 0 ? 0 : (bn_ > XBINS - 1 ? XBINS - 1 : bn_);
    rlo[q] = cumb[bn_];
    bn_ = (int)((me[q].x + rT + 1e-5f + XOFF) * XSCALE);
    bn_ = bn_ < 0 ? 0 : (bn_ > XBINS - 1 ? XBINS - 1 : bn_);
    rhi[q] = cumb[bn_ + 1];
    rloU = rlo[q] < rloU ? rlo[q] : rloU;
    rhiU = rhi[q] > rhiU ? rhi[q] : rhiU;
  }

  // ---- pass 1: one scan of the union window serves all 4 rows ----
  for (int j0 = rloU; j0 < rhiU; j0 += 128) {
    #pragma unroll
    for (int t = 0; t < 2; ++t) {
      int j = j0 + t * 64 + lane;
      if (j < rhiU) {
        float4 p = sxb[j];
        #pragma unroll
        for (int q = 0; q < 4; ++q) {
          float inner = fmaf(p.x, me[q].x, fmaf(p.y, me[q].y, p.z * me[q].z));
          float d = fmaf(-2.0f, inner, me[q].w + p.w);
          if (d < Tup[q]) {
            int bb = (int)__float_as_uint(d);
            unsigned sk = (unsigned)(bb ^ ((bb >> 31) | 0x80000000));
            unsigned c = atomicAdd(&ccnt[wid][q], 1u);
            if (c < CAP)
              cdk[wid][q][c] = ((unsigned long long)sk << 32) | (unsigned)ordb[j];
          }
        }
      }
    }
  }

  // ---- per-row epilogue: refine (rare) + select ----
  #pragma unroll
  for (int q = 0; q < 4; ++q) {
    int cnt = (int)ccnt[wid][q];            // same-wave DS ordering -> appends visible
    float TupQ = Tup[q];
    int rloQ = rlo[q], rhiQ = rhi[q];

    for (int it = 0; cnt > CAP && it < 4; ++it) {
      hist[wid][q][lane] = 0u;
      const float s56 = 56.0f / TupQ;
      for (int j0 = rloQ; j0 < rhiQ; j0 += 64) {
        int j = j0 + lane;
        if (j < rhiQ) {
          float4 p = sxb[j];
          float inner = fmaf(p.x, me[q].x, fmaf(p.y, me[q].y, p.z * me[q].z));
          float d = fmaf(-2.0f, inner, me[q].w + p.w);
          int bk = (int)(d * s56);           // d<0 (self, fp) -> 0 via trunc
          if ((unsigned)bk < (unsigned)NBUCK) atomicAdd(&hist[wid][q][bk], 1u);
        }
      }
      unsigned cum2 = (lane < NBUCK) ? hist[wid][q][lane] : 0u;
      #pragma unroll
      for (int off = 1; off < 64; off <<= 1) {
        unsigned o = __shfl_up(cum2, off);
        if (lane >= off) cum2 += o;
      }
      int crit2 = __popcll(__ballot(lane < NBUCK && cum2 < KK));  // <= 55
      unsigned cnew = __shfl(cum2, crit2);
      if (cnew <= CAP) {
        if (lane == 0) ccnt[wid][q] = 0u;
        for (int j0 = rloQ; j0 < rhiQ; j0 += 64) {
          int j = j0 + lane;
          if (j < rhiQ) {
            float4 p = sxb[j];
            float inner = fmaf(p.x, me[q].x, fmaf(p.y, me[q].y, p.z * me[q].z));
            float d = fmaf(-2.0f, inner, me[q].w + p.w);
            int bk = (int)(d * s56);
            if (bk <= crit2) {
              int bb = (int)__float_as_uint(d);
              unsigned sk = (unsigned)(bb ^ ((bb >> 31) | 0x80000000));
              unsigned c = atomicAdd(&ccnt[wid][q], 1u);
              if (c < CAP)
                cdk[wid][q][c] = ((unsigned long long)sk << 32) | (unsigned)ordb[j];
            }
          }
        }
        cnt = (int)ccnt[wid][q];             // == cnew <= CAP
        break;
      }
      TupQ = (float)(crit2 + 1) * (TupQ / 56.0f);
      float rT = sqrtf(TupQ);
      int bn_ = (int)((me[q].x - rT - 1e-5f + XOFF) * XSCALE);
      bn_ = bn_ < 0 ? 0 : (bn_ > XBINS - 1 ? XBINS - 1 : bn_);
      rloQ = cumb[bn_];
      bn_ = (int)((me[q].x + rT + 1e-5f + XOFF) * XSCALE);
      bn_ = bn_ < 0 ? 0 : (bn_ > XBINS - 1 ? XBINS - 1 : bn_);
      rhiQ = cumb[bn_ + 1];
      cnt = (int)cnew;
    }

    const int nOrig = ordb[r0 + q];
    int* op = idx_out + (b * Nn + nOrig) * KK;

    if (cnt <= CAP) {
      // rank selection (keys distinct via orig idx; (d, idx)-lex == jax top_k tie-break)
      for (int c = lane; c < cnt; c += 64) {
        unsigned long long key = cdk[wid][q][c];
        int rank = 0;
        for (int c2 = 0; c2 < cnt; ++c2) rank += (cdk[wid][q][c2] < key) ? 1 : 0;
        if (rank < KK) op[rank] = (int)(key & 0xFFFFFFFFu);
      }
    } else {
      // ultimate exact path: 20 rounds of wave-min, strictly-increasing keys
      unsigned long long last = 0ull;
      for (int k = 0; k < KK; ++k) {
        unsigned long long best = ~0ull;
        for (int j0 = rloQ; j0 < rhiQ; j0 += 64) {
          int j = j0 + lane;
          if (j < rhiQ) {
            float4 p = sxb[j];
            float inner = fmaf(p.x, me[q].x, fmaf(p.y, me[q].y, p.z * me[q].z));
            float d = fmaf(-2.0f, inner, me[q].w + p.w);
            int bb = (int)__float_as_uint(d);
            unsigned sk = (unsigned)(bb ^ ((bb >> 31) | 0x80000000));
            unsigned long long key = ((unsigned long long)sk << 32) | (unsigned)ordb[j];
            if (key > last && key < best) best = key;
          }
        }
        #pragma unroll
        for (int off = 32; off >= 1; off >>= 1) {
          unsigned lo_ = (unsigned)best, hi_ = (unsigned)(best >> 32);
          unsigned olo = __shfl_xor(lo_, off), ohi = __shfl_xor(hi_, off);
          unsigned long long o = ((unsigned long long)ohi << 32) | olo;
          if (o < best) best = o;
        }
        if (lane == 0) op[k] = (int)(best & 0xFFFFFFFFu);
        last = best;
      }
    }
  }
}

// ---------------- u = (Wa-Wb)·x_n, v = Wb·x_n  (layout [b][n][o], o contiguous) -------------

__global__ __launch_bounds__(256) void uv_kernel(const float* __restrict__ x,
                                                 const float* __restrict__ W,
                                                 float* __restrict__ u,
                                                 float* __restrict__ v) {
  int gid = blockIdx.x * 256 + threadIdx.x;
  int o  = gid & 63;
  int bn = gid >> 6;
  int b  = bn >> 13;
  int n  = bn & (Nn - 1);
  const float* xb = x + b * 3 * Nn;
  float x0 = xb[n], x1 = xb[Nn + n], x2 = xb[2 * Nn + n];
  float wa0 = W[o * 6 + 0], wa1 = W[o * 6 + 1], wa2 = W[o * 6 + 2];
  float wb0 = W[o * 6 + 3], wb1 = W[o * 6 + 4], wb2 = W[o * 6 + 5];
  u[gid] = (wa0 - wb0) * x0 + (wa1 - wb1) * x1 + (wa2 - wb2) * x2;
  v[gid] = wb0 * x0 + wb1 * x1 + wb2 * x2;
}

// ---------------- gather v over neighbors: pm = u + max_k v ; accumulate S1,S2 --------------

__global__ __launch_bounds__(256) void gather_kernel(const int* __restrict__ idx,
                                                     float* __restrict__ u,      // in-place -> pm
                                                     const float* __restrict__ v,
                                                     float* __restrict__ stats) {
  __shared__ float ls1[4][64], ls2[4][64];
  int b  = blockIdx.y;
  int o  = threadIdx.x & 63;
  int ys = threadIdx.x >> 6;
  const float* vb = v + (size_t)b * Nn * OO;
  float s1 = 0.f, s2 = 0.f;
  for (int i = 0; i < 16; ++i) {
    int n = blockIdx.x * 64 + ys * 16 + i;
    const int* ip = idx + (b * Nn + n) * KK;
    float un = u[(size_t)(b * Nn + n) * OO + o];
    float sv = 0.f, sv2 = 0.f, mv = -__builtin_inff();
    #pragma unroll
    for (int k = 0; k < KK; ++k) {
      int j = ip[k];
      float val = vb[(size_t)j * OO + o];
      sv += val; sv2 += val * val; mv = fmaxf(mv, val);
    }
    u[(size_t)(b * Nn + n) * OO + o] = un + mv;
    s1 += (float)KK * un + sv;
    s2 += (float)KK * un * un + 2.f * un * sv + sv2;
  }
  ls1[ys][o] = s1; ls2[ys][o] = s2;
  __syncthreads();
  if (ys == 0) {
    float t1 = ls1[0][o] + ls1[1][o] + ls1[2][o] + ls1[3][o];
    float t2 = ls2[0][o] + ls2[1][o] + ls2[2][o] + ls2[3][o];
    atomicAdd(&stats[(b * OO + o) * 2 + 0], t1);
    atomicAdd(&stats[(b * OO + o) * 2 + 1], t2);
  }
}

// ---------------- finalize: normalize + lrelu + transpose to [b][o][n] ----------------------

__global__ __launch_bounds__(256) void out_kernel(const float* __restrict__ pm,
                                                  const float* __restrict__ stats,
                                                  float* __restrict__ out) {
  __shared__ float tile[64][65];
  int b  = blockIdx.y;
  int o  = threadIdx.x & 63;
  int ys = threadIdx.x >> 6;
  const float inv_cnt = 1.0f / (float)(Nn * KK);
  float S1 = stats[(b * OO + o) * 2 + 0];
  float S2 = stats[(b * OO + o) * 2 + 1];
  float mean = S1 * inv_cnt;
  float var  = S2 * inv_cnt - mean * mean;
  float istd = rsqrtf(var + EPSF);
  for (int i = 0; i < 16; ++i) {
    int n = blockIdx.x * 64 + ys * 16 + i;
    float val = (pm[(size_t)(b * Nn + n) * OO + o] - mean) * istd;
    val = (val >= 0.f) ? val : SLOPEF * val;
    tile[ys * 16 + i][o] = val;
  }
  __syncthreads();
  int nb = blockIdx.x * 64;
  for (int i = 0; i < 16; ++i) {
    int oo = ys * 16 + i;
    out[(size_t)(b * OO + oo) * Nn + nb + o] = tile[o][oo];
  }
}

// ---------------- launch ---------------------------------------------------------------------

extern "C" void kernel_launch(void* const* d_in, const int* in_sizes, int n_in,
                              void* d_out, int out_size, void* d_ws, size_t ws_size,
                              hipStream_t stream) {
  const float* x = (const float*)d_in[0];
  const float* W = (const float*)d_in[1];
  float* out = (float*)d_out;

  char* ws = (char*)d_ws;
  int*    idx   = (int*)ws;                         // 2,621,440 B
  float*  u     = (float*)(ws + 2621440);           // 8,388,608 B (becomes pm)
  float*  v     = (float*)(ws + 11010048);          // 8,388,608 B
  float*  stats = (float*)(ws + 19398656);          // 4,096 B
  float4* sx    = (float4*)(ws + 19402752);         // 524,288 B (16B aligned)
  int*    ord   = (int*)(ws + 19927040);            // 131,072 B
  int*    cumg  = (int*)(ws + 20058112);            // 4,112 B

  hipMemsetAsync(stats, 0, Bb * OO * 2 * sizeof(float), stream);
  sort_kernel  <<<Bb, 1024, 0, stream>>>(x, sx, ord, cumg);
  uv_kernel    <<<dim3((Bb * Nn * OO) / 256), 256, 0, stream>>>(x, W, u, v);
  knn_kernel   <<<dim3(512, Bb), 256, 0, stream>>>(sx, ord, cumg, idx);
  gather_kernel<<<dim3(128, Bb), 256, 0, stream>>>(idx, u, v, stats);
  out_kernel   <<<dim3(128, Bb), 256, 0, stream>>>(u, stats, out);
}